// Round 2
// baseline (2823.980 us; speedup 1.0000x reference)
//
#include <hip/hip_runtime.h>

#define WAVE 64

// rT layout: [layer][N_R][64]  (batch innermost, matches lane)
// One block per batch row b; q-row staged in LDS; threads sweep (layer, j).
__global__ void compute_r_kernel(const float* __restrict__ q,
                                 const float* __restrict__ W1, const float* __restrict__ b1,
                                 const float* __restrict__ W2, const float* __restrict__ b2,
                                 const float* __restrict__ W3, const float* __restrict__ b3,
                                 float* __restrict__ rT, int N_R, int N_W2V) {
    __shared__ float qs[512];
    int b = blockIdx.x;  // 0..63
    for (int k = threadIdx.x; k < N_W2V; k += blockDim.x)
        qs[k] = q[(size_t)b * N_W2V + k];
    __syncthreads();
    for (int it = threadIdx.x; it < 3 * N_R; it += blockDim.x) {
        int l = it / N_R;
        int j = it - l * N_R;
        const float* W  = (l == 0) ? W1 : (l == 1) ? W2 : W3;
        const float* bv = (l == 0) ? b1 : (l == 1) ? b2 : b3;
        float acc = bv[j];
        for (int k = 0; k < N_W2V; ++k)
            acc = fmaf(qs[k], W[(size_t)k * N_R + j], acc);  // lanes: consecutive j -> coalesced
        rT[(size_t)it * WAVE + b] = acc;
    }
}

// x (B=64, N_E) -> xT (N_E, 64), 64x64 LDS tile transpose
__global__ void transpose_in_kernel(const float* __restrict__ in, float* __restrict__ out, int N_E) {
    __shared__ float tile[64][65];
    int e0 = blockIdx.x * 64;
    int li = threadIdx.x & 63;   // inner lane
    int lo = threadIdx.x >> 6;   // 0..3
    #pragma unroll
    for (int k = 0; k < 16; ++k) {
        int b = lo + 4 * k;
        int e = e0 + li;
        tile[b][li] = (e < N_E) ? in[(size_t)b * N_E + e] : 0.0f;
    }
    __syncthreads();
    #pragma unroll
    for (int k = 0; k < 16; ++k) {
        int i = lo + 4 * k;
        int e = e0 + i;
        if (e < N_E) out[(size_t)e * 64 + li] = tile[li][i];
    }
}

// xT (N_E, 64) -> out (B=64, N_E)
__global__ void transpose_out_kernel(const float* __restrict__ in, float* __restrict__ out, int N_E) {
    __shared__ float tile[64][65];
    int e0 = blockIdx.x * 64;
    int li = threadIdx.x & 63;
    int lo = threadIdx.x >> 6;
    #pragma unroll
    for (int k = 0; k < 16; ++k) {
        int i = lo + 4 * k;
        int e = e0 + i;
        tile[i][li] = (e < N_E) ? in[(size_t)e * 64 + li] : 0.0f;  // lane li = batch, coalesced
    }
    __syncthreads();
    #pragma unroll
    for (int k = 0; k < 16; ++k) {
        int b = lo + 4 * k;
        int e = e0 + li;
        if (e < N_E) out[(size_t)b * N_E + e] = tile[li][b];       // lane li = entity, coalesced
    }
}

// 16 lanes per triple, float4 per lane (256B/triple, coalesced). 4 triples/wave,
// manual unroll x2 -> 8 triples in flight per wave. Native fp32 atomics.
__global__ void hop_kernel(const float4* __restrict__ xT4, const float4* __restrict__ rT4,
                           const int* __restrict__ subj, const int* __restrict__ rel,
                           const int* __restrict__ obj, float* __restrict__ yT, int nT) {
    int gid = blockIdx.x * blockDim.x + threadIdx.x;
    int grp = gid >> 4;          // triple group
    int sub = gid & 15;          // float4 slot within the 64-wide batch row
    int ngr = (gridDim.x * blockDim.x) >> 4;

    int t = grp;
    for (; t + ngr < nT; t += 2 * ngr) {
        int t1 = t + ngr;
        int s0 = subj[t],  r0 = rel[t],  o0 = obj[t];
        int s1 = subj[t1], r1 = rel[t1], o1 = obj[t1];
        float4 xv0 = xT4[(size_t)s0 * 16 + sub];
        float4 rv0 = rT4[(size_t)r0 * 16 + sub];
        float4 xv1 = xT4[(size_t)s1 * 16 + sub];
        float4 rv1 = rT4[(size_t)r1 * 16 + sub];
        float* yp0 = yT + (size_t)o0 * 64 + sub * 4;
        float* yp1 = yT + (size_t)o1 * 64 + sub * 4;
        unsafeAtomicAdd(yp0 + 0, xv0.x * rv0.x);
        unsafeAtomicAdd(yp0 + 1, xv0.y * rv0.y);
        unsafeAtomicAdd(yp0 + 2, xv0.z * rv0.z);
        unsafeAtomicAdd(yp0 + 3, xv0.w * rv0.w);
        unsafeAtomicAdd(yp1 + 0, xv1.x * rv1.x);
        unsafeAtomicAdd(yp1 + 1, xv1.y * rv1.y);
        unsafeAtomicAdd(yp1 + 2, xv1.z * rv1.z);
        unsafeAtomicAdd(yp1 + 3, xv1.w * rv1.w);
    }
    for (; t < nT; t += ngr) {
        int s = subj[t], r = rel[t], o = obj[t];
        float4 xv = xT4[(size_t)s * 16 + sub];
        float4 rv = rT4[(size_t)r * 16 + sub];
        float* yp = yT + (size_t)o * 64 + sub * 4;
        unsafeAtomicAdd(yp + 0, xv.x * rv.x);
        unsafeAtomicAdd(yp + 1, xv.y * rv.y);
        unsafeAtomicAdd(yp + 2, xv.z * rv.z);
        unsafeAtomicAdd(yp + 3, xv.w * rv.w);
    }
}

extern "C" void kernel_launch(void* const* d_in, const int* in_sizes, int n_in,
                              void* d_out, int out_size, void* d_ws, size_t ws_size,
                              hipStream_t stream) {
    const float* x  = (const float*)d_in[0];
    const float* q  = (const float*)d_in[1];
    const float* W1 = (const float*)d_in[2];
    const float* b1 = (const float*)d_in[3];
    const float* W2 = (const float*)d_in[4];
    const float* b2 = (const float*)d_in[5];
    const float* W3 = (const float*)d_in[6];
    const float* b3 = (const float*)d_in[7];
    const int* subj = (const int*)d_in[8];
    const int* rel  = (const int*)d_in[9];
    const int* obj  = (const int*)d_in[10];
    // n_hop (d_in[11]) is the constant 3 per the reference; hops hardcoded.

    const int B     = 64;                // == wave size; lane = batch row
    const int N_E   = in_sizes[0] / B;   // 200000
    const int N_W2V = in_sizes[1] / B;   // 300
    const int N_R   = in_sizes[3];       // 200
    const int N_T   = in_sizes[8];       // 1000000

    const size_t xelems = (size_t)N_E * B;
    const size_t xbytes = xelems * sizeof(float);
    const size_t rbytes = (size_t)3 * N_R * B * sizeof(float);

    float* bufA = (float*)d_ws;
    float* bufB;
    float* rT;
    bool b_is_out;
    if (ws_size >= 2 * xbytes + rbytes) {
        bufB = bufA + xelems;
        rT   = bufB + xelems;
        b_is_out = false;
    } else {
        bufB = (float*)d_out;            // use d_out as ping-pong buffer
        rT   = bufA + xelems;
        b_is_out = true;
    }

    // 1) r = q@W + b for all three layers, transposed layout
    compute_r_kernel<<<B, 256, 0, stream>>>(q, W1, b1, W2, b2, W3, b3, rT, N_R, N_W2V);

    // 2) transpose x -> bufA (entity-major)
    int tgrid = (N_E + 63) / 64;
    transpose_in_kernel<<<tgrid, 256, 0, stream>>>(x, bufA, N_E);

    // 3) three hops, ping-pong
    const int HOP_BLOCKS = 2048;   // 32768 triple-groups, grid-stride over 1M triples
    hipMemsetAsync(bufB, 0, xbytes, stream);
    hop_kernel<<<HOP_BLOCKS, 256, 0, stream>>>((const float4*)bufA, (const float4*)rT,
                                               subj, rel, obj, bufB, N_T);
    hipMemsetAsync(bufA, 0, xbytes, stream);
    hop_kernel<<<HOP_BLOCKS, 256, 0, stream>>>((const float4*)bufB, (const float4*)(rT + (size_t)1 * N_R * B),
                                               subj, rel, obj, bufA, N_T);
    hipMemsetAsync(bufB, 0, xbytes, stream);
    hop_kernel<<<HOP_BLOCKS, 256, 0, stream>>>((const float4*)bufA, (const float4*)(rT + (size_t)2 * N_R * B),
                                               subj, rel, obj, bufB, N_T);

    // 4) transpose back to (B, N_E)
    if (!b_is_out) {
        transpose_out_kernel<<<tgrid, 256, 0, stream>>>(bufB, (float*)d_out, N_E);
    } else {
        transpose_out_kernel<<<tgrid, 256, 0, stream>>>(bufB, bufA, N_E);
        hipMemcpyAsync(d_out, bufA, xbytes, hipMemcpyDeviceToDevice, stream);
    }
}

// Round 3
// 907.564 us; speedup vs baseline: 3.1116x; 3.1116x over previous
//
#include <hip/hip_runtime.h>

#define WAVE 64

// rT layout: [layer][N_R][64]  (batch innermost, matches lane)
// One block per batch row b; q-row staged in LDS; threads sweep (layer, j).
__global__ void compute_r_kernel(const float* __restrict__ q,
                                 const float* __restrict__ W1, const float* __restrict__ b1,
                                 const float* __restrict__ W2, const float* __restrict__ b2,
                                 const float* __restrict__ W3, const float* __restrict__ b3,
                                 float* __restrict__ rT, int N_R, int N_W2V) {
    __shared__ float qs[512];
    int b = blockIdx.x;  // 0..63
    for (int k = threadIdx.x; k < N_W2V; k += blockDim.x)
        qs[k] = q[(size_t)b * N_W2V + k];
    __syncthreads();
    for (int it = threadIdx.x; it < 3 * N_R; it += blockDim.x) {
        int l = it / N_R;
        int j = it - l * N_R;
        const float* W  = (l == 0) ? W1 : (l == 1) ? W2 : W3;
        const float* bv = (l == 0) ? b1 : (l == 1) ? b2 : b3;
        float acc = bv[j];
        for (int k = 0; k < N_W2V; ++k)
            acc = fmaf(qs[k], W[(size_t)k * N_R + j], acc);  // lanes: consecutive j -> coalesced
        rT[(size_t)it * WAVE + b] = acc;
    }
}

// x (B=64, N_E) -> xT (N_E, 64), 64x64 LDS tile transpose
__global__ void transpose_in_kernel(const float* __restrict__ in, float* __restrict__ out, int N_E) {
    __shared__ float tile[64][65];
    int e0 = blockIdx.x * 64;
    int li = threadIdx.x & 63;   // inner lane
    int lo = threadIdx.x >> 6;   // 0..3
    #pragma unroll
    for (int k = 0; k < 16; ++k) {
        int b = lo + 4 * k;
        int e = e0 + li;
        tile[b][li] = (e < N_E) ? in[(size_t)b * N_E + e] : 0.0f;
    }
    __syncthreads();
    #pragma unroll
    for (int k = 0; k < 16; ++k) {
        int i = lo + 4 * k;
        int e = e0 + i;
        if (e < N_E) out[(size_t)e * 64 + li] = tile[li][i];
    }
}

// xT (N_E, 64) -> out (B=64, N_E)
__global__ void transpose_out_kernel(const float* __restrict__ in, float* __restrict__ out, int N_E) {
    __shared__ float tile[64][65];
    int e0 = blockIdx.x * 64;
    int li = threadIdx.x & 63;
    int lo = threadIdx.x >> 6;
    #pragma unroll
    for (int k = 0; k < 16; ++k) {
        int i = lo + 4 * k;
        int e = e0 + i;
        tile[i][li] = (e < N_E) ? in[(size_t)e * 64 + li] : 0.0f;  // lane li = batch, coalesced
    }
    __syncthreads();
    #pragma unroll
    for (int k = 0; k < 16; ++k) {
        int b = lo + 4 * k;
        int e = e0 + li;
        if (e < N_E) out[(size_t)b * N_E + e] = tile[li][b];       // lane li = entity, coalesced
    }
}

// One wave per 64 consecutive triples; lane = batch row.
// Indices prefetched coalesced (lane i holds triple t0+i), broadcast via __shfl.
// 4 independent gather->fma->atomic chains in flight; every atomic is a full
// 64-lane x 4B contiguous instruction (256B/triple) -- keeps HBM write
// coalescing (R2 lesson: scalar strided atomics caused 4x write amplification).
__global__ void hop_kernel(const float* __restrict__ xT, const float* __restrict__ rT,
                           const int* __restrict__ subj, const int* __restrict__ rel,
                           const int* __restrict__ obj, float* __restrict__ yT, int nT) {
    int lane = threadIdx.x & 63;
    int wave = (blockIdx.x * blockDim.x + threadIdx.x) >> 6;
    int t0 = wave * 64;
    if (t0 >= nT) return;
    int tl = t0 + lane;
    bool valid = tl < nT;
    int sv = valid ? subj[tl] : 0;
    int rv = valid ? rel[tl]  : 0;
    int ov = valid ? obj[tl]  : 0;
    int cnt = min(64, nT - t0);

    int i = 0;
    for (; i + 4 <= cnt; i += 4) {
        int s0 = __shfl(sv, i),     r0 = __shfl(rv, i),     o0 = __shfl(ov, i);
        int s1 = __shfl(sv, i + 1), r1 = __shfl(rv, i + 1), o1 = __shfl(ov, i + 1);
        int s2 = __shfl(sv, i + 2), r2 = __shfl(rv, i + 2), o2 = __shfl(ov, i + 2);
        int s3 = __shfl(sv, i + 3), r3 = __shfl(rv, i + 3), o3 = __shfl(ov, i + 3);
        float x0 = xT[(size_t)s0 * 64 + lane];
        float x1 = xT[(size_t)s1 * 64 + lane];
        float x2 = xT[(size_t)s2 * 64 + lane];
        float x3 = xT[(size_t)s3 * 64 + lane];
        float a0 = rT[(size_t)r0 * 64 + lane];
        float a1 = rT[(size_t)r1 * 64 + lane];
        float a2 = rT[(size_t)r2 * 64 + lane];
        float a3 = rT[(size_t)r3 * 64 + lane];
        atomicAdd(&yT[(size_t)o0 * 64 + lane], x0 * a0);
        atomicAdd(&yT[(size_t)o1 * 64 + lane], x1 * a1);
        atomicAdd(&yT[(size_t)o2 * 64 + lane], x2 * a2);
        atomicAdd(&yT[(size_t)o3 * 64 + lane], x3 * a3);
    }
    for (; i < cnt; ++i) {
        int s = __shfl(sv, i), r = __shfl(rv, i), o = __shfl(ov, i);
        atomicAdd(&yT[(size_t)o * 64 + lane],
                  xT[(size_t)s * 64 + lane] * rT[(size_t)r * 64 + lane]);
    }
}

extern "C" void kernel_launch(void* const* d_in, const int* in_sizes, int n_in,
                              void* d_out, int out_size, void* d_ws, size_t ws_size,
                              hipStream_t stream) {
    const float* x  = (const float*)d_in[0];
    const float* q  = (const float*)d_in[1];
    const float* W1 = (const float*)d_in[2];
    const float* b1 = (const float*)d_in[3];
    const float* W2 = (const float*)d_in[4];
    const float* b2 = (const float*)d_in[5];
    const float* W3 = (const float*)d_in[6];
    const float* b3 = (const float*)d_in[7];
    const int* subj = (const int*)d_in[8];
    const int* rel  = (const int*)d_in[9];
    const int* obj  = (const int*)d_in[10];
    // n_hop (d_in[11]) is the constant 3 per the reference; hops hardcoded.

    const int B     = 64;                // == wave size; lane = batch row
    const int N_E   = in_sizes[0] / B;   // 200000
    const int N_W2V = in_sizes[1] / B;   // 300
    const int N_R   = in_sizes[3];       // 200
    const int N_T   = in_sizes[8];       // 1000000

    const size_t xelems = (size_t)N_E * B;
    const size_t xbytes = xelems * sizeof(float);
    const size_t rbytes = (size_t)3 * N_R * B * sizeof(float);

    float* bufA = (float*)d_ws;
    float* bufB;
    float* rT;
    bool b_is_out;
    if (ws_size >= 2 * xbytes + rbytes) {
        bufB = bufA + xelems;
        rT   = bufB + xelems;
        b_is_out = false;
    } else {
        bufB = (float*)d_out;            // use d_out as ping-pong buffer
        rT   = bufA + xelems;
        b_is_out = true;
    }

    // 1) r = q@W + b for all three layers, transposed layout
    compute_r_kernel<<<B, 256, 0, stream>>>(q, W1, b1, W2, b2, W3, b3, rT, N_R, N_W2V);

    // 2) transpose x -> bufA (entity-major)
    int tgrid = (N_E + 63) / 64;
    transpose_in_kernel<<<tgrid, 256, 0, stream>>>(x, bufA, N_E);

    // 3) three hops, ping-pong. One wave per 64 triples.
    int nwaves = (N_T + 63) / 64;                 // 15625
    int hop_blocks = (nwaves + 3) / 4;            // 4 waves per 256-thread block
    hipMemsetAsync(bufB, 0, xbytes, stream);
    hop_kernel<<<hop_blocks, 256, 0, stream>>>(bufA, rT, subj, rel, obj, bufB, N_T);
    hipMemsetAsync(bufA, 0, xbytes, stream);
    hop_kernel<<<hop_blocks, 256, 0, stream>>>(bufB, rT + (size_t)1 * N_R * B, subj, rel, obj, bufA, N_T);
    hipMemsetAsync(bufB, 0, xbytes, stream);
    hop_kernel<<<hop_blocks, 256, 0, stream>>>(bufA, rT + (size_t)2 * N_R * B, subj, rel, obj, bufB, N_T);

    // 4) transpose back to (B, N_E)
    if (!b_is_out) {
        transpose_out_kernel<<<tgrid, 256, 0, stream>>>(bufB, (float*)d_out, N_E);
    } else {
        transpose_out_kernel<<<tgrid, 256, 0, stream>>>(bufB, bufA, N_E);
        hipMemcpyAsync(d_out, bufA, xbytes, hipMemcpyDeviceToDevice, stream);
    }
}

// Round 4
// 557.833 us; speedup vs baseline: 5.0624x; 1.6269x over previous
//
#include <hip/hip_runtime.h>

#define WAVE 64

// rT layout: [layer][N_R][64]  (batch innermost, matches lane)
__global__ void compute_r_kernel(const float* __restrict__ q,
                                 const float* __restrict__ W1, const float* __restrict__ b1,
                                 const float* __restrict__ W2, const float* __restrict__ b2,
                                 const float* __restrict__ W3, const float* __restrict__ b3,
                                 float* __restrict__ rT, int N_R, int N_W2V) {
    __shared__ float qs[512];
    int b = blockIdx.x;  // 0..63
    for (int k = threadIdx.x; k < N_W2V; k += blockDim.x)
        qs[k] = q[(size_t)b * N_W2V + k];
    __syncthreads();
    for (int it = threadIdx.x; it < 3 * N_R; it += blockDim.x) {
        int l = it / N_R;
        int j = it - l * N_R;
        const float* W  = (l == 0) ? W1 : (l == 1) ? W2 : W3;
        const float* bv = (l == 0) ? b1 : (l == 1) ? b2 : b3;
        float acc = bv[j];
        for (int k = 0; k < N_W2V; ++k)
            acc = fmaf(qs[k], W[(size_t)k * N_R + j], acc);
        rT[(size_t)it * WAVE + b] = acc;
    }
}

// x (B=64, N_E) -> xT (N_E, 64)
__global__ void transpose_in_kernel(const float* __restrict__ in, float* __restrict__ out, int N_E) {
    __shared__ float tile[64][65];
    int e0 = blockIdx.x * 64;
    int li = threadIdx.x & 63;
    int lo = threadIdx.x >> 6;
    #pragma unroll
    for (int k = 0; k < 16; ++k) {
        int b = lo + 4 * k;
        int e = e0 + li;
        tile[b][li] = (e < N_E) ? in[(size_t)b * N_E + e] : 0.0f;
    }
    __syncthreads();
    #pragma unroll
    for (int k = 0; k < 16; ++k) {
        int i = lo + 4 * k;
        int e = e0 + i;
        if (e < N_E) out[(size_t)e * 64 + li] = tile[li][i];
    }
}

// xT (N_E, 64) -> out (B=64, N_E)
__global__ void transpose_out_kernel(const float* __restrict__ in, float* __restrict__ out, int N_E) {
    __shared__ float tile[64][65];
    int e0 = blockIdx.x * 64;
    int li = threadIdx.x & 63;
    int lo = threadIdx.x >> 6;
    #pragma unroll
    for (int k = 0; k < 16; ++k) {
        int i = lo + 4 * k;
        int e = e0 + i;
        tile[i][li] = (e < N_E) ? in[(size_t)e * 64 + li] : 0.0f;
    }
    __syncthreads();
    #pragma unroll
    for (int k = 0; k < 16; ++k) {
        int b = lo + 4 * k;
        int e = e0 + li;
        if (e < N_E) out[(size_t)b * N_E + e] = tile[li][b];
    }
}

// ---- CSR build: counts -> 3-phase exclusive scan -> scatter permutation ----

__global__ void count_kernel(const int* __restrict__ obj, int* __restrict__ counts, int nT) {
    int t = blockIdx.x * blockDim.x + threadIdx.x;
    if (t < nT) atomicAdd(&counts[obj[t]], 1);
}

__global__ void scanA_kernel(const int* __restrict__ counts, int* __restrict__ partials, int nE) {
    __shared__ int lds[256];
    int i = blockIdx.x * 256 + threadIdx.x;
    lds[threadIdx.x] = (i < nE) ? counts[i] : 0;
    __syncthreads();
    for (int off = 128; off > 0; off >>= 1) {
        if (threadIdx.x < off) lds[threadIdx.x] += lds[threadIdx.x + off];
        __syncthreads();
    }
    if (threadIdx.x == 0) partials[blockIdx.x] = lds[0];
}

// single block, nP <= 1024 (here nP = ceil(200000/256) = 782)
__global__ void scanB_kernel(int* __restrict__ partials, int nP) {
    __shared__ int lds[1024];
    int tid = threadIdx.x;
    lds[tid] = (tid < nP) ? partials[tid] : 0;
    __syncthreads();
    for (int off = 1; off < 1024; off <<= 1) {
        int v = (tid >= off) ? lds[tid - off] : 0;
        __syncthreads();
        lds[tid] += v;
        __syncthreads();
    }
    if (tid < nP) partials[tid] = (tid == 0) ? 0 : lds[tid - 1];
}

__global__ void scanC_kernel(const int* __restrict__ counts, const int* __restrict__ partials,
                             int* __restrict__ row_ptr, int* __restrict__ cursor, int nE) {
    __shared__ int lds[256];
    int i = blockIdx.x * 256 + threadIdx.x;
    int c = (i < nE) ? counts[i] : 0;
    lds[threadIdx.x] = c;
    __syncthreads();
    for (int off = 1; off < 256; off <<= 1) {
        int v = (threadIdx.x >= off) ? lds[threadIdx.x - off] : 0;
        __syncthreads();
        lds[threadIdx.x] += v;
        __syncthreads();
    }
    int excl = partials[blockIdx.x] + ((threadIdx.x == 0) ? 0 : lds[threadIdx.x - 1]);
    if (i < nE) { row_ptr[i] = excl; cursor[i] = excl; }
    if (i == nE - 1) row_ptr[nE] = excl + c;
}

// packed = subj | (rel<<18). Valid for N_E < 2^18=262144, N_R < 2^14 (here 200000/200).
__global__ void scatter_kernel(const int* __restrict__ subj, const int* __restrict__ rel,
                               const int* __restrict__ obj, int* __restrict__ cursor,
                               unsigned* __restrict__ packed, int nT) {
    int t = blockIdx.x * blockDim.x + threadIdx.x;
    if (t >= nT) return;
    int slot = atomicAdd(&cursor[obj[t]], 1);
    packed[slot] = (unsigned)subj[t] | ((unsigned)rel[t] << 18);
}

// One wave per output entity; lane = batch row. Zero atomics (R3 lesson:
// atomic path is hard-walled at ~305 G dword-RMW/s = L2 channel-cycle rate).
// Bucket's packed indices prefetched coalesced, broadcast via __shfl.
// One coalesced 256B plain store per entity (no output memset needed).
__global__ void hop_csr_kernel(const float* __restrict__ xT, const float* __restrict__ rT,
                               const int* __restrict__ row_ptr, const unsigned* __restrict__ packed,
                               float* __restrict__ yT, int nE) {
    int lane = threadIdx.x & 63;
    int e = (blockIdx.x * blockDim.x + threadIdx.x) >> 6;
    if (e >= nE) return;
    int beg = row_ptr[e];
    int end = row_ptr[e + 1];
    int len = end - beg;
    float acc0 = 0.0f, acc1 = 0.0f;
    if (len <= 64) {
        unsigned pv = (lane < len) ? packed[beg + lane] : 0u;
        int j = 0;
        for (; j + 2 <= len; j += 2) {
            unsigned p0 = __shfl(pv, j);
            unsigned p1 = __shfl(pv, j + 1);
            acc0 += xT[(size_t)(p0 & 0x3FFFFu) * 64 + lane] * rT[(size_t)(p0 >> 18) * 64 + lane];
            acc1 += xT[(size_t)(p1 & 0x3FFFFu) * 64 + lane] * rT[(size_t)(p1 >> 18) * 64 + lane];
        }
        if (j < len) {
            unsigned p = __shfl(pv, j);
            acc0 += xT[(size_t)(p & 0x3FFFFu) * 64 + lane] * rT[(size_t)(p >> 18) * 64 + lane];
        }
    } else {
        for (int i = beg; i < end; ++i) {
            unsigned p = packed[i];
            acc0 += xT[(size_t)(p & 0x3FFFFu) * 64 + lane] * rT[(size_t)(p >> 18) * 64 + lane];
        }
    }
    yT[(size_t)e * 64 + lane] = acc0 + acc1;
}

extern "C" void kernel_launch(void* const* d_in, const int* in_sizes, int n_in,
                              void* d_out, int out_size, void* d_ws, size_t ws_size,
                              hipStream_t stream) {
    const float* x  = (const float*)d_in[0];
    const float* q  = (const float*)d_in[1];
    const float* W1 = (const float*)d_in[2];
    const float* b1 = (const float*)d_in[3];
    const float* W2 = (const float*)d_in[4];
    const float* b2 = (const float*)d_in[5];
    const float* W3 = (const float*)d_in[6];
    const float* b3 = (const float*)d_in[7];
    const int* subj = (const int*)d_in[8];
    const int* rel  = (const int*)d_in[9];
    const int* obj  = (const int*)d_in[10];
    // n_hop (d_in[11]) is the constant 3 per the reference; hops hardcoded.

    const int B     = 64;
    const int N_E   = in_sizes[0] / B;   // 200000
    const int N_W2V = in_sizes[1] / B;   // 300
    const int N_R   = in_sizes[3];       // 200
    const int N_T   = in_sizes[8];       // 1000000

    const size_t xelems = (size_t)N_E * B;
    const size_t xbytes = xelems * sizeof(float);
    const size_t rbytes = (size_t)3 * N_R * B * sizeof(float);

    // workspace layout: [counts nE][row_ptr nE+1][cursor nE][packed nT][rT][bufA][bufB?]
    int*      counts  = (int*)d_ws;
    int*      row_ptr = counts + N_E;
    int*      cursor  = row_ptr + (N_E + 1);
    unsigned* packed  = (unsigned*)(cursor + N_E);
    float*    rT      = (float*)(packed + N_T);
    float*    bufA    = rT + (size_t)3 * N_R * B;
    size_t used = (size_t)((char*)bufA - (char*)d_ws) + xbytes;

    float* bufB;
    bool b_is_out;
    if (ws_size >= used + xbytes) {
        bufB = bufA + xelems;
        b_is_out = false;
    } else {
        bufB = (float*)d_out;
        b_is_out = true;
    }

    // 1) r for all three layers
    compute_r_kernel<<<B, 256, 0, stream>>>(q, W1, b1, W2, b2, W3, b3, rT, N_R, N_W2V);

    // 2) transpose x -> bufA
    int tgrid = (N_E + 63) / 64;
    transpose_in_kernel<<<tgrid, 256, 0, stream>>>(x, bufA, N_E);

    // 3) CSR build (counts -> scan -> scatter)
    int nScan = (N_E + 255) / 256;                 // 782 <= 1024
    int* partials = cursor;                        // reuse cursor space pre-scanC (needs nScan ints)
    // careful: scanC writes cursor; partials must survive until scanC reads it.
    // cursor[0..nScan) used as partials, cursor rewritten by scanC AFTER reading
    // partials[blockIdx.x] -- same array: scanC reads partials[blockIdx.x] before
    // any write to cursor[i] with i == blockIdx.x*256.. only if blockIdx < nScan and
    // overlap: partials[g] == cursor[g]; cursor[g] is written by block g/256.. NOT safe.
    // Use a separate small region instead: place partials after packed's end? packed
    // has exactly nT slots all written later. Simplest: allocate partials inside rT
    // region? rT already computed. Place partials at end of used region:
    partials = (int*)(bufA + xelems - 0);          // overwrite? NO.
    // -> give partials its own slot right before bufA by shifting bufA is risky;
    // instead reuse counts' tail? counts fully live. Use d_out head when b_is_out
    // is false; otherwise steal 4KB after bufB. Safer: steal the last 4KB of ws.
    partials = (int*)((char*)d_ws + ws_size - 4096);
    if ((size_t)((char*)partials - (char*)d_ws) < used + (b_is_out ? 0 : xbytes)) {
        // ws too tight for a tail slab: fall back to reusing packed's last 1024 ints
        // (packed is only written AFTER scanC completes, so this is safe).
        partials = (int*)(packed + N_T) - 1024;    // inside packed region
        partials = (int*)packed + (N_T - 1024);
    }

    hipMemsetAsync(counts, 0, (size_t)N_E * sizeof(int), stream);
    int cgrid = (N_T + 255) / 256;
    count_kernel<<<cgrid, 256, 0, stream>>>(obj, counts, N_T);
    scanA_kernel<<<nScan, 256, 0, stream>>>(counts, partials, N_E);
    scanB_kernel<<<1, 1024, 0, stream>>>(partials, nScan);
    scanC_kernel<<<nScan, 256, 0, stream>>>(counts, partials, row_ptr, cursor, N_E);
    scatter_kernel<<<cgrid, 256, 0, stream>>>(subj, rel, obj, cursor, packed, N_T);

    // 4) three hops, ping-pong, no atomics, no output memsets
    int hgrid = ((N_E * 64) + 255) / 256;          // one wave per entity
    hop_csr_kernel<<<hgrid, 256, 0, stream>>>(bufA, rT,                          row_ptr, packed, bufB, N_E);
    hop_csr_kernel<<<hgrid, 256, 0, stream>>>(bufB, rT + (size_t)1 * N_R * B,    row_ptr, packed, bufA, N_E);
    hop_csr_kernel<<<hgrid, 256, 0, stream>>>(bufA, rT + (size_t)2 * N_R * B,    row_ptr, packed, bufB, N_E);

    // 5) transpose back
    if (!b_is_out) {
        transpose_out_kernel<<<tgrid, 256, 0, stream>>>(bufB, (float*)d_out, N_E);
    } else {
        transpose_out_kernel<<<tgrid, 256, 0, stream>>>(bufB, bufA, N_E);
        hipMemcpyAsync(d_out, bufA, xbytes, hipMemcpyDeviceToDevice, stream);
    }
}

// Round 5
// 497.277 us; speedup vs baseline: 5.6789x; 1.1218x over previous
//
#include <hip/hip_runtime.h>

#define WAVE 64

// rT layout: [layer][N_R][64]  (batch innermost, matches lane)
// Wave-parallel: each wave = one batch row b x 64 (layer,j) items.
// Grid (ceil(3*N_R/64), B/4), block 256 = 4 waves. Lane -> consecutive j
// (coalesced W reads); q[b][k] wave-uniform; k-loop unrolled x4 to break
// the fmaf dependency chain (R4 lesson: 64-block version was latency-bound
// at 2.4% occupancy, 98 us for an 11.5 MFLOP GEMM).
__global__ void compute_r_kernel(const float* __restrict__ q,
                                 const float* __restrict__ W1, const float* __restrict__ b1,
                                 const float* __restrict__ W2, const float* __restrict__ b2,
                                 const float* __restrict__ W3, const float* __restrict__ b3,
                                 float* __restrict__ rT, int N_R, int N_W2V) {
    int lane = threadIdx.x & 63;
    int wv   = threadIdx.x >> 6;              // 0..3
    int b    = blockIdx.y * 4 + wv;           // batch row, wave-uniform
    int it   = blockIdx.x * 64 + lane;        // flat (layer, j)
    if (it >= 3 * N_R) return;
    int l = it / N_R;
    int j = it - l * N_R;
    const float* W  = (l == 0) ? W1 : (l == 1) ? W2 : W3;
    const float* bv = (l == 0) ? b1 : (l == 1) ? b2 : b3;
    const float* qrow = q + (size_t)b * N_W2V;
    float a0 = 0.f, a1 = 0.f, a2 = 0.f, a3 = 0.f;
    int k = 0;
    for (; k + 4 <= N_W2V; k += 4) {
        a0 = fmaf(qrow[k + 0], W[(size_t)(k + 0) * N_R + j], a0);
        a1 = fmaf(qrow[k + 1], W[(size_t)(k + 1) * N_R + j], a1);
        a2 = fmaf(qrow[k + 2], W[(size_t)(k + 2) * N_R + j], a2);
        a3 = fmaf(qrow[k + 3], W[(size_t)(k + 3) * N_R + j], a3);
    }
    for (; k < N_W2V; ++k)
        a0 = fmaf(qrow[k], W[(size_t)k * N_R + j], a0);
    rT[(size_t)it * WAVE + b] = bv[j] + ((a0 + a1) + (a2 + a3));
}

// x (B=64, N_E) -> xT (N_E, 64)
__global__ void transpose_in_kernel(const float* __restrict__ in, float* __restrict__ out, int N_E) {
    __shared__ float tile[64][65];
    int e0 = blockIdx.x * 64;
    int li = threadIdx.x & 63;
    int lo = threadIdx.x >> 6;
    #pragma unroll
    for (int k = 0; k < 16; ++k) {
        int b = lo + 4 * k;
        int e = e0 + li;
        tile[b][li] = (e < N_E) ? in[(size_t)b * N_E + e] : 0.0f;
    }
    __syncthreads();
    #pragma unroll
    for (int k = 0; k < 16; ++k) {
        int i = lo + 4 * k;
        int e = e0 + i;
        if (e < N_E) out[(size_t)e * 64 + li] = tile[li][i];
    }
}

// xT (N_E, 64) -> out (B=64, N_E)
__global__ void transpose_out_kernel(const float* __restrict__ in, float* __restrict__ out, int N_E) {
    __shared__ float tile[64][65];
    int e0 = blockIdx.x * 64;
    int li = threadIdx.x & 63;
    int lo = threadIdx.x >> 6;
    #pragma unroll
    for (int k = 0; k < 16; ++k) {
        int i = lo + 4 * k;
        int e = e0 + i;
        tile[i][li] = (e < N_E) ? in[(size_t)e * 64 + li] : 0.0f;
    }
    __syncthreads();
    #pragma unroll
    for (int k = 0; k < 16; ++k) {
        int b = lo + 4 * k;
        int e = e0 + li;
        if (e < N_E) out[(size_t)b * N_E + e] = tile[li][b];
    }
}

// ---- CSR build: counts -> 3-phase exclusive scan -> scatter permutation ----

__global__ void count_kernel(const int* __restrict__ obj, int* __restrict__ counts, int nT) {
    int t = blockIdx.x * blockDim.x + threadIdx.x;
    if (t < nT) atomicAdd(&counts[obj[t]], 1);
}

__global__ void scanA_kernel(const int* __restrict__ counts, int* __restrict__ partials, int nE) {
    __shared__ int lds[256];
    int i = blockIdx.x * 256 + threadIdx.x;
    lds[threadIdx.x] = (i < nE) ? counts[i] : 0;
    __syncthreads();
    for (int off = 128; off > 0; off >>= 1) {
        if (threadIdx.x < off) lds[threadIdx.x] += lds[threadIdx.x + off];
        __syncthreads();
    }
    if (threadIdx.x == 0) partials[blockIdx.x] = lds[0];
}

// single block, nP <= 1024 (here nP = ceil(200000/256) = 782)
__global__ void scanB_kernel(int* __restrict__ partials, int nP) {
    __shared__ int lds[1024];
    int tid = threadIdx.x;
    lds[tid] = (tid < nP) ? partials[tid] : 0;
    __syncthreads();
    for (int off = 1; off < 1024; off <<= 1) {
        int v = (tid >= off) ? lds[tid - off] : 0;
        __syncthreads();
        lds[tid] += v;
        __syncthreads();
    }
    if (tid < nP) partials[tid] = (tid == 0) ? 0 : lds[tid - 1];
}

__global__ void scanC_kernel(const int* __restrict__ counts, const int* __restrict__ partials,
                             int* __restrict__ row_ptr, int* __restrict__ cursor, int nE) {
    __shared__ int lds[256];
    int i = blockIdx.x * 256 + threadIdx.x;
    int c = (i < nE) ? counts[i] : 0;
    lds[threadIdx.x] = c;
    __syncthreads();
    for (int off = 1; off < 256; off <<= 1) {
        int v = (threadIdx.x >= off) ? lds[threadIdx.x - off] : 0;
        __syncthreads();
        lds[threadIdx.x] += v;
        __syncthreads();
    }
    int excl = partials[blockIdx.x] + ((threadIdx.x == 0) ? 0 : lds[threadIdx.x - 1]);
    if (i < nE) { row_ptr[i] = excl; cursor[i] = excl; }
    if (i == nE - 1) row_ptr[nE] = excl + c;
}

// packed = subj | (rel<<18). Valid for N_E < 2^18=262144, N_R < 2^14 (here 200000/200).
__global__ void scatter_kernel(const int* __restrict__ subj, const int* __restrict__ rel,
                               const int* __restrict__ obj, int* __restrict__ cursor,
                               unsigned* __restrict__ packed, int nT) {
    int t = blockIdx.x * blockDim.x + threadIdx.x;
    if (t >= nT) return;
    int slot = atomicAdd(&cursor[obj[t]], 1);
    packed[slot] = (unsigned)subj[t] | ((unsigned)rel[t] << 18);
}

// One wave per output entity; lane = batch row. Zero atomics (R3 lesson:
// atomic path is hard-walled at ~305 G dword-RMW/s = L2 channel-cycle rate).
// Bucket's packed indices prefetched coalesced, broadcast via __shfl.
// One coalesced 256B plain store per entity (no output memset needed).
__global__ void hop_csr_kernel(const float* __restrict__ xT, const float* __restrict__ rT,
                               const int* __restrict__ row_ptr, const unsigned* __restrict__ packed,
                               float* __restrict__ yT, int nE) {
    int lane = threadIdx.x & 63;
    int e = (blockIdx.x * blockDim.x + threadIdx.x) >> 6;
    if (e >= nE) return;
    int beg = row_ptr[e];
    int end = row_ptr[e + 1];
    int len = end - beg;
    float acc0 = 0.0f, acc1 = 0.0f;
    if (len <= 64) {
        unsigned pv = (lane < len) ? packed[beg + lane] : 0u;
        int j = 0;
        for (; j + 2 <= len; j += 2) {
            unsigned p0 = __shfl(pv, j);
            unsigned p1 = __shfl(pv, j + 1);
            acc0 += xT[(size_t)(p0 & 0x3FFFFu) * 64 + lane] * rT[(size_t)(p0 >> 18) * 64 + lane];
            acc1 += xT[(size_t)(p1 & 0x3FFFFu) * 64 + lane] * rT[(size_t)(p1 >> 18) * 64 + lane];
        }
        if (j < len) {
            unsigned p = __shfl(pv, j);
            acc0 += xT[(size_t)(p & 0x3FFFFu) * 64 + lane] * rT[(size_t)(p >> 18) * 64 + lane];
        }
    } else {
        for (int i = beg; i < end; ++i) {
            unsigned p = packed[i];
            acc0 += xT[(size_t)(p & 0x3FFFFu) * 64 + lane] * rT[(size_t)(p >> 18) * 64 + lane];
        }
    }
    yT[(size_t)e * 64 + lane] = acc0 + acc1;
}

extern "C" void kernel_launch(void* const* d_in, const int* in_sizes, int n_in,
                              void* d_out, int out_size, void* d_ws, size_t ws_size,
                              hipStream_t stream) {
    const float* x  = (const float*)d_in[0];
    const float* q  = (const float*)d_in[1];
    const float* W1 = (const float*)d_in[2];
    const float* b1 = (const float*)d_in[3];
    const float* W2 = (const float*)d_in[4];
    const float* b2 = (const float*)d_in[5];
    const float* W3 = (const float*)d_in[6];
    const float* b3 = (const float*)d_in[7];
    const int* subj = (const int*)d_in[8];
    const int* rel  = (const int*)d_in[9];
    const int* obj  = (const int*)d_in[10];
    // n_hop (d_in[11]) is the constant 3 per the reference; hops hardcoded.

    const int B     = 64;
    const int N_E   = in_sizes[0] / B;   // 200000
    const int N_W2V = in_sizes[1] / B;   // 300
    const int N_R   = in_sizes[3];       // 200
    const int N_T   = in_sizes[8];       // 1000000

    const size_t xelems = (size_t)N_E * B;
    const size_t xbytes = xelems * sizeof(float);

    // workspace layout: [counts nE][row_ptr nE+1][cursor nE][packed nT][rT][bufA][bufB?]
    int*      counts  = (int*)d_ws;
    int*      row_ptr = counts + N_E;
    int*      cursor  = row_ptr + (N_E + 1);
    unsigned* packed  = (unsigned*)(cursor + N_E);
    float*    rT      = (float*)(packed + N_T);
    float*    bufA    = rT + (size_t)3 * N_R * B;
    size_t used = (size_t)((char*)bufA - (char*)d_ws) + xbytes;

    float* bufB;
    bool b_is_out;
    if (ws_size >= used + xbytes) {
        bufB = bufA + xelems;
        b_is_out = false;
    } else {
        bufB = (float*)d_out;
        b_is_out = true;
    }

    // scan partials (nScan ints): steal the tail of ws if free, else the tail of
    // packed (safe: packed is only written by scatter AFTER scanC consumed partials).
    int nScan = (N_E + 255) / 256;                 // 782
    int* partials = (int*)((char*)d_ws + ws_size - 4096);
    if ((size_t)((char*)partials - (char*)d_ws) < used + (b_is_out ? 0 : xbytes))
        partials = (int*)packed + (N_T - 1024);

    // 1) r for all three layers (160 blocks, 640 waves)
    {
        dim3 rgrid((3 * N_R + 63) / 64, B / 4);
        compute_r_kernel<<<rgrid, 256, 0, stream>>>(q, W1, b1, W2, b2, W3, b3, rT, N_R, N_W2V);
    }

    // 2) transpose x -> bufA
    int tgrid = (N_E + 63) / 64;
    transpose_in_kernel<<<tgrid, 256, 0, stream>>>(x, bufA, N_E);

    // 3) CSR build (counts -> scan -> scatter)
    hipMemsetAsync(counts, 0, (size_t)N_E * sizeof(int), stream);
    int cgrid = (N_T + 255) / 256;
    count_kernel<<<cgrid, 256, 0, stream>>>(obj, counts, N_T);
    scanA_kernel<<<nScan, 256, 0, stream>>>(counts, partials, N_E);
    scanB_kernel<<<1, 1024, 0, stream>>>(partials, nScan);
    scanC_kernel<<<nScan, 256, 0, stream>>>(counts, partials, row_ptr, cursor, N_E);
    scatter_kernel<<<cgrid, 256, 0, stream>>>(subj, rel, obj, cursor, packed, N_T);

    // 4) three hops, ping-pong, no atomics, no output memsets
    int hgrid = ((N_E * 64) + 255) / 256;          // one wave per entity
    hop_csr_kernel<<<hgrid, 256, 0, stream>>>(bufA, rT,                          row_ptr, packed, bufB, N_E);
    hop_csr_kernel<<<hgrid, 256, 0, stream>>>(bufB, rT + (size_t)1 * N_R * B,    row_ptr, packed, bufA, N_E);
    hop_csr_kernel<<<hgrid, 256, 0, stream>>>(bufA, rT + (size_t)2 * N_R * B,    row_ptr, packed, bufB, N_E);

    // 5) transpose back
    if (!b_is_out) {
        transpose_out_kernel<<<tgrid, 256, 0, stream>>>(bufB, (float*)d_out, N_E);
    } else {
        transpose_out_kernel<<<tgrid, 256, 0, stream>>>(bufB, bufA, N_E);
        hipMemcpyAsync(d_out, bufA, xbytes, hipMemcpyDeviceToDevice, stream);
    }
}

// Round 6
// 486.262 us; speedup vs baseline: 5.8075x; 1.0227x over previous
//
#include <hip/hip_runtime.h>

#define WAVE 64
#define NXCD 8

// rT layout: [layer][N_R][64]  (batch innermost, matches lane)
__global__ void compute_r_kernel(const float* __restrict__ q,
                                 const float* __restrict__ W1, const float* __restrict__ b1,
                                 const float* __restrict__ W2, const float* __restrict__ b2,
                                 const float* __restrict__ W3, const float* __restrict__ b3,
                                 float* __restrict__ rT, int N_R, int N_W2V) {
    int lane = threadIdx.x & 63;
    int wv   = threadIdx.x >> 6;
    int b    = blockIdx.y * 4 + wv;
    int it   = blockIdx.x * 64 + lane;
    if (it >= 3 * N_R) return;
    int l = it / N_R;
    int j = it - l * N_R;
    const float* W  = (l == 0) ? W1 : (l == 1) ? W2 : W3;
    const float* bv = (l == 0) ? b1 : (l == 1) ? b2 : b3;
    const float* qrow = q + (size_t)b * N_W2V;
    float a0 = 0.f, a1 = 0.f, a2 = 0.f, a3 = 0.f;
    int k = 0;
    for (; k + 4 <= N_W2V; k += 4) {
        a0 = fmaf(qrow[k + 0], W[(size_t)(k + 0) * N_R + j], a0);
        a1 = fmaf(qrow[k + 1], W[(size_t)(k + 1) * N_R + j], a1);
        a2 = fmaf(qrow[k + 2], W[(size_t)(k + 2) * N_R + j], a2);
        a3 = fmaf(qrow[k + 3], W[(size_t)(k + 3) * N_R + j], a3);
    }
    for (; k < N_W2V; ++k)
        a0 = fmaf(qrow[k], W[(size_t)k * N_R + j], a0);
    rT[(size_t)it * WAVE + b] = bv[j] + ((a0 + a1) + (a2 + a3));
}

// x (B=64, N_E) -> xT (N_E, 64)
__global__ void transpose_in_kernel(const float* __restrict__ in, float* __restrict__ out, int N_E) {
    __shared__ float tile[64][65];
    int e0 = blockIdx.x * 64;
    int li = threadIdx.x & 63;
    int lo = threadIdx.x >> 6;
    #pragma unroll
    for (int k = 0; k < 16; ++k) {
        int b = lo + 4 * k;
        int e = e0 + li;
        tile[b][li] = (e < N_E) ? in[(size_t)b * N_E + e] : 0.0f;
    }
    __syncthreads();
    #pragma unroll
    for (int k = 0; k < 16; ++k) {
        int i = lo + 4 * k;
        int e = e0 + i;
        if (e < N_E) out[(size_t)e * 64 + li] = tile[li][i];
    }
}

// ---- CSR build ----
// R5 lesson: un-sharded random 4B scatter writes cost 17x HBM write
// amplification (71MB for a 4MB array) because 64B lines are dirtied in
// multiple non-coherent XCD L2s. Fix: group g = blockIdx%8 (round-robin
// block->XCD heuristic) owns entity range [g*sh, (g+1)*sh); each group scans
// all obj (L2/L3-resident, cheap) and only touches its own counts/packed
// slice -> each dirty line lives in exactly one XCD L2, flushed once.

__global__ void count_kernel(const int* __restrict__ obj, int* __restrict__ counts,
                             int nT, int nE) {
    int grp = blockIdx.x & (NXCD - 1);
    int sh  = (nE + NXCD - 1) / NXCD;
    int lo  = grp * sh;
    int hi  = min(nE, lo + sh);
    int tid    = (blockIdx.x >> 3) * blockDim.x + threadIdx.x;
    int stride = (gridDim.x >> 3) * blockDim.x;
    for (int t = tid; t < nT; t += stride) {
        int o = obj[t];
        if (o >= lo && o < hi) atomicAdd(&counts[o], 1);
    }
}

__global__ void scanA_kernel(const int* __restrict__ counts, int* __restrict__ partials, int nE) {
    __shared__ int lds[256];
    int i = blockIdx.x * 256 + threadIdx.x;
    lds[threadIdx.x] = (i < nE) ? counts[i] : 0;
    __syncthreads();
    for (int off = 128; off > 0; off >>= 1) {
        if (threadIdx.x < off) lds[threadIdx.x] += lds[threadIdx.x + off];
        __syncthreads();
    }
    if (threadIdx.x == 0) partials[blockIdx.x] = lds[0];
}

// single block, nP <= 1024 (here nP = ceil(200000/256) = 782)
__global__ void scanB_kernel(int* __restrict__ partials, int nP) {
    __shared__ int lds[1024];
    int tid = threadIdx.x;
    lds[tid] = (tid < nP) ? partials[tid] : 0;
    __syncthreads();
    for (int off = 1; off < 1024; off <<= 1) {
        int v = (tid >= off) ? lds[tid - off] : 0;
        __syncthreads();
        lds[tid] += v;
        __syncthreads();
    }
    if (tid < nP) partials[tid] = (tid == 0) ? 0 : lds[tid - 1];
}

__global__ void scanC_kernel(const int* __restrict__ counts, const int* __restrict__ partials,
                             int* __restrict__ row_ptr, int* __restrict__ cursor, int nE) {
    __shared__ int lds[256];
    int i = blockIdx.x * 256 + threadIdx.x;
    int c = (i < nE) ? counts[i] : 0;
    lds[threadIdx.x] = c;
    __syncthreads();
    for (int off = 1; off < 256; off <<= 1) {
        int v = (threadIdx.x >= off) ? lds[threadIdx.x - off] : 0;
        __syncthreads();
        lds[threadIdx.x] += v;
        __syncthreads();
    }
    int excl = partials[blockIdx.x] + ((threadIdx.x == 0) ? 0 : lds[threadIdx.x - 1]);
    if (i < nE) { row_ptr[i] = excl; cursor[i] = excl; }
    if (i == nE - 1) row_ptr[nE] = excl + c;
}

// packed = subj | (rel<<18). Valid for N_E < 2^18, N_R < 2^14 (here 200000/200).
__global__ void scatter_kernel(const int* __restrict__ subj, const int* __restrict__ rel,
                               const int* __restrict__ obj, int* __restrict__ cursor,
                               unsigned* __restrict__ packed, int nT, int nE) {
    int grp = blockIdx.x & (NXCD - 1);
    int sh  = (nE + NXCD - 1) / NXCD;
    int lo  = grp * sh;
    int hi  = min(nE, lo + sh);
    int tid    = (blockIdx.x >> 3) * blockDim.x + threadIdx.x;
    int stride = (gridDim.x >> 3) * blockDim.x;
    for (int t = tid; t < nT; t += stride) {
        int o = obj[t];
        if (o >= lo && o < hi) {
            int slot = atomicAdd(&cursor[o], 1);
            packed[slot] = (unsigned)subj[t] | ((unsigned)rel[t] << 18);
        }
    }
}

// Per-entity accumulation: bucket's packed indices prefetched coalesced,
// broadcast via __shfl; zero atomics (R3: atomic path walls at ~305G RMW/s).
__device__ inline float hop_accum(const float* __restrict__ xT, const float* __restrict__ rT,
                                  const int* __restrict__ row_ptr,
                                  const unsigned* __restrict__ packed, int e, int lane) {
    int beg = row_ptr[e];
    int end = row_ptr[e + 1];
    int len = end - beg;
    float acc0 = 0.0f, acc1 = 0.0f;
    if (len <= 64) {
        unsigned pv = (lane < len) ? packed[beg + lane] : 0u;
        int j = 0;
        for (; j + 2 <= len; j += 2) {
            unsigned p0 = __shfl(pv, j);
            unsigned p1 = __shfl(pv, j + 1);
            acc0 += xT[(size_t)(p0 & 0x3FFFFu) * 64 + lane] * rT[(size_t)(p0 >> 18) * 64 + lane];
            acc1 += xT[(size_t)(p1 & 0x3FFFFu) * 64 + lane] * rT[(size_t)(p1 >> 18) * 64 + lane];
        }
        if (j < len) {
            unsigned p = __shfl(pv, j);
            acc0 += xT[(size_t)(p & 0x3FFFFu) * 64 + lane] * rT[(size_t)(p >> 18) * 64 + lane];
        }
    } else {
        for (int i = beg; i < end; ++i) {
            unsigned p = packed[i];
            acc0 += xT[(size_t)(p & 0x3FFFFu) * 64 + lane] * rT[(size_t)(p >> 18) * 64 + lane];
        }
    }
    return acc0 + acc1;
}

// hops 1-2: one wave per entity, output in (N_E, 64) layout
__global__ void hop_csr_kernel(const float* __restrict__ xT, const float* __restrict__ rT,
                               const int* __restrict__ row_ptr, const unsigned* __restrict__ packed,
                               float* __restrict__ yT, int nE) {
    int lane = threadIdx.x & 63;
    int e = (blockIdx.x * blockDim.x + threadIdx.x) >> 6;
    if (e >= nE) return;
    yT[(size_t)e * 64 + lane] = hop_accum(xT, rT, row_ptr, packed, e, lane);
}

// hop 3 fused with output transpose: block handles 64 entities, accumulates
// into an LDS tile, stores directly in (B, N_E) layout (kills the separate
// 51MB+51MB transpose_out pass).
__global__ void hop_csr_out_kernel(const float* __restrict__ xT, const float* __restrict__ rT,
                                   const int* __restrict__ row_ptr, const unsigned* __restrict__ packed,
                                   float* __restrict__ out, int nE) {
    __shared__ float tile[64][65];
    int lane = threadIdx.x & 63;
    int wv   = threadIdx.x >> 6;    // 0..3
    int e0   = blockIdx.x * 64;
    for (int i = wv; i < 64; i += 4) {
        int e = e0 + i;
        tile[i][lane] = (e < nE) ? hop_accum(xT, rT, row_ptr, packed, e, lane) : 0.0f;
    }
    __syncthreads();
    #pragma unroll
    for (int k = 0; k < 16; ++k) {
        int b = wv + 4 * k;
        int e = e0 + lane;
        if (e < nE) out[(size_t)b * nE + e] = tile[lane][b];
    }
}

extern "C" void kernel_launch(void* const* d_in, const int* in_sizes, int n_in,
                              void* d_out, int out_size, void* d_ws, size_t ws_size,
                              hipStream_t stream) {
    const float* x  = (const float*)d_in[0];
    const float* q  = (const float*)d_in[1];
    const float* W1 = (const float*)d_in[2];
    const float* b1 = (const float*)d_in[3];
    const float* W2 = (const float*)d_in[4];
    const float* b2 = (const float*)d_in[5];
    const float* W3 = (const float*)d_in[6];
    const float* b3 = (const float*)d_in[7];
    const int* subj = (const int*)d_in[8];
    const int* rel  = (const int*)d_in[9];
    const int* obj  = (const int*)d_in[10];
    // n_hop (d_in[11]) is the constant 3 per the reference; hops hardcoded.

    const int B     = 64;
    const int N_E   = in_sizes[0] / B;   // 200000
    const int N_W2V = in_sizes[1] / B;   // 300
    const int N_R   = in_sizes[3];       // 200
    const int N_T   = in_sizes[8];       // 1000000

    const size_t xelems = (size_t)N_E * B;
    const size_t xbytes = xelems * sizeof(float);

    // workspace layout: [counts nE][row_ptr nE+1][cursor nE][packed nT][rT][bufA][bufB?]
    int*      counts  = (int*)d_ws;
    int*      row_ptr = counts + N_E;
    int*      cursor  = row_ptr + (N_E + 1);
    unsigned* packed  = (unsigned*)(cursor + N_E);
    float*    rT      = (float*)(packed + N_T);
    float*    bufA    = rT + (size_t)3 * N_R * B;
    size_t used = (size_t)((char*)bufA - (char*)d_ws) + xbytes;

    float* bufB;
    if (ws_size >= used + xbytes) {
        bufB = bufA + xelems;
    } else {
        bufB = (float*)d_out;   // d_out as mid-run scratch (yT layout); final
                                // write comes from hop_csr_out_kernel anyway
    }

    // scan partials: steal tail of ws if free, else tail of packed (safe:
    // packed written only after scanC consumed partials).
    int nScan = (N_E + 255) / 256;       // 782
    int* partials = (int*)((char*)d_ws + ws_size - 4096);
    if ((size_t)((char*)partials - (char*)d_ws) < used + ((bufB == (float*)d_out) ? 0 : xbytes))
        partials = (int*)packed + (N_T - 1024);

    // 1) r for all three layers
    {
        dim3 rgrid((3 * N_R + 63) / 64, B / 4);
        compute_r_kernel<<<rgrid, 256, 0, stream>>>(q, W1, b1, W2, b2, W3, b3, rT, N_R, N_W2V);
    }

    // 2) transpose x -> bufA
    int tgrid = (N_E + 63) / 64;
    transpose_in_kernel<<<tgrid, 256, 0, stream>>>(x, bufA, N_E);

    // 3) CSR build (XCD-sharded count -> scan -> XCD-sharded scatter)
    hipMemsetAsync(counts, 0, (size_t)N_E * sizeof(int), stream);
    count_kernel<<<1024, 256, 0, stream>>>(obj, counts, N_T, N_E);
    scanA_kernel<<<nScan, 256, 0, stream>>>(counts, partials, N_E);
    scanB_kernel<<<1, 1024, 0, stream>>>(partials, nScan);
    scanC_kernel<<<nScan, 256, 0, stream>>>(counts, partials, row_ptr, cursor, N_E);
    scatter_kernel<<<1024, 256, 0, stream>>>(subj, rel, obj, cursor, packed, N_T, N_E);

    // 4) three hops; hop3 fuses the output transpose
    int hgrid = ((N_E * 64) + 255) / 256;    // one wave per entity
    hop_csr_kernel<<<hgrid, 256, 0, stream>>>(bufA, rT,                       row_ptr, packed, bufB, N_E);
    hop_csr_kernel<<<hgrid, 256, 0, stream>>>(bufB, rT + (size_t)1 * N_R * B, row_ptr, packed, bufA, N_E);
    hop_csr_out_kernel<<<tgrid, 256, 0, stream>>>(bufA, rT + (size_t)2 * N_R * B, row_ptr, packed,
                                                  (float*)d_out, N_E);
}

// Round 7
// 455.146 us; speedup vs baseline: 6.2046x; 1.0684x over previous
//
#include <hip/hip_runtime.h>

#define WAVE 64
#define NXCD 8

// rT layout: [layer][N_R][64]  (batch innermost, matches lane)
__global__ void compute_r_kernel(const float* __restrict__ q,
                                 const float* __restrict__ W1, const float* __restrict__ b1,
                                 const float* __restrict__ W2, const float* __restrict__ b2,
                                 const float* __restrict__ W3, const float* __restrict__ b3,
                                 float* __restrict__ rT, int N_R, int N_W2V) {
    int lane = threadIdx.x & 63;
    int wv   = threadIdx.x >> 6;
    int b    = blockIdx.y * 4 + wv;
    int it   = blockIdx.x * 64 + lane;
    if (it >= 3 * N_R) return;
    int l = it / N_R;
    int j = it - l * N_R;
    const float* W  = (l == 0) ? W1 : (l == 1) ? W2 : W3;
    const float* bv = (l == 0) ? b1 : (l == 1) ? b2 : b3;
    const float* qrow = q + (size_t)b * N_W2V;
    float a0 = 0.f, a1 = 0.f, a2 = 0.f, a3 = 0.f;
    int k = 0;
    for (; k + 4 <= N_W2V; k += 4) {
        a0 = fmaf(qrow[k + 0], W[(size_t)(k + 0) * N_R + j], a0);
        a1 = fmaf(qrow[k + 1], W[(size_t)(k + 1) * N_R + j], a1);
        a2 = fmaf(qrow[k + 2], W[(size_t)(k + 2) * N_R + j], a2);
        a3 = fmaf(qrow[k + 3], W[(size_t)(k + 3) * N_R + j], a3);
    }
    for (; k < N_W2V; ++k)
        a0 = fmaf(qrow[k], W[(size_t)k * N_R + j], a0);
    rT[(size_t)it * WAVE + b] = bv[j] + ((a0 + a1) + (a2 + a3));
}

// x (B=64, N_E) -> xT (N_E, 64)
__global__ void transpose_in_kernel(const float* __restrict__ in, float* __restrict__ out, int N_E) {
    __shared__ float tile[64][65];
    int e0 = blockIdx.x * 64;
    int li = threadIdx.x & 63;
    int lo = threadIdx.x >> 6;
    #pragma unroll
    for (int k = 0; k < 16; ++k) {
        int b = lo + 4 * k;
        int e = e0 + li;
        tile[b][li] = (e < N_E) ? in[(size_t)b * N_E + e] : 0.0f;
    }
    __syncthreads();
    #pragma unroll
    for (int k = 0; k < 16; ++k) {
        int i = lo + 4 * k;
        int e = e0 + i;
        if (e < N_E) out[(size_t)e * 64 + li] = tile[li][i];
    }
}

// ---- CSR build ----
// R5 lesson: un-sharded random 4B scatter writes cost 17x HBM write
// amplification (64B lines dirtied in multiple non-coherent XCD L2s).
// Group g = blockIdx%8 owns entity range; only touches its own slice.

__global__ void count_kernel(const int* __restrict__ obj, int* __restrict__ counts,
                             int nT, int nE) {
    int grp = blockIdx.x & (NXCD - 1);
    int sh  = (nE + NXCD - 1) / NXCD;
    int lo  = grp * sh;
    int hi  = min(nE, lo + sh);
    int tid    = (blockIdx.x >> 3) * blockDim.x + threadIdx.x;
    int stride = (gridDim.x >> 3) * blockDim.x;
    for (int t = tid; t < nT; t += stride) {
        int o = obj[t];
        if (o >= lo && o < hi) atomicAdd(&counts[o], 1);
    }
}

__global__ void scanA_kernel(const int* __restrict__ counts, int* __restrict__ partials, int nE) {
    __shared__ int lds[256];
    int i = blockIdx.x * 256 + threadIdx.x;
    lds[threadIdx.x] = (i < nE) ? counts[i] : 0;
    __syncthreads();
    for (int off = 128; off > 0; off >>= 1) {
        if (threadIdx.x < off) lds[threadIdx.x] += lds[threadIdx.x + off];
        __syncthreads();
    }
    if (threadIdx.x == 0) partials[blockIdx.x] = lds[0];
}

// single block, nP <= 1024 (here nP = ceil(200000/256) = 782)
__global__ void scanB_kernel(int* __restrict__ partials, int nP) {
    __shared__ int lds[1024];
    int tid = threadIdx.x;
    lds[tid] = (tid < nP) ? partials[tid] : 0;
    __syncthreads();
    for (int off = 1; off < 1024; off <<= 1) {
        int v = (tid >= off) ? lds[tid - off] : 0;
        __syncthreads();
        lds[tid] += v;
        __syncthreads();
    }
    if (tid < nP) partials[tid] = (tid == 0) ? 0 : lds[tid - 1];
}

__global__ void scanC_kernel(const int* __restrict__ counts, const int* __restrict__ partials,
                             int* __restrict__ row_ptr, int* __restrict__ cursor, int nE) {
    __shared__ int lds[256];
    int i = blockIdx.x * 256 + threadIdx.x;
    int c = (i < nE) ? counts[i] : 0;
    lds[threadIdx.x] = c;
    __syncthreads();
    for (int off = 1; off < 256; off <<= 1) {
        int v = (threadIdx.x >= off) ? lds[threadIdx.x - off] : 0;
        __syncthreads();
        lds[threadIdx.x] += v;
        __syncthreads();
    }
    int excl = partials[blockIdx.x] + ((threadIdx.x == 0) ? 0 : lds[threadIdx.x - 1]);
    if (i < nE) { row_ptr[i] = excl; cursor[i] = excl; }
    if (i == nE - 1) row_ptr[nE] = excl + c;
}

// packed = subj | (rel<<18). Valid for N_E < 2^18, N_R < 2^14 (here 200000/200).
__global__ void scatter_kernel(const int* __restrict__ subj, const int* __restrict__ rel,
                               const int* __restrict__ obj, int* __restrict__ cursor,
                               unsigned* __restrict__ packed, int nT, int nE) {
    int grp = blockIdx.x & (NXCD - 1);
    int sh  = (nE + NXCD - 1) / NXCD;
    int lo  = grp * sh;
    int hi  = min(nE, lo + sh);
    int tid    = (blockIdx.x >> 3) * blockDim.x + threadIdx.x;
    int stride = (gridDim.x >> 3) * blockDim.x;
    for (int t = tid; t < nT; t += stride) {
        int o = obj[t];
        if (o >= lo && o < hi) {
            int slot = atomicAdd(&cursor[o], 1);
            packed[slot] = (unsigned)subj[t] | ((unsigned)rel[t] << 18);
        }
    }
}

// Per-entity accumulation, MLP-restructured (R6 lesson: hop was latency-bound
// with only ~2 gathers in flight/wave; FETCH 176MB/hop @ 3TB/s is NOT a BW
// wall). Chunk of 8: issue all 16 gathers into distinct regs before any FMA
// -> one waitcnt per chunk, ~16 outstanding misses/wave. Tail is branch-free
// via clamp-to-last (dup loads hit the just-fetched line). Zero atomics.
__device__ inline float hop_accum(const float* __restrict__ xT, const float* __restrict__ rT,
                                  const int* __restrict__ row_ptr,
                                  const unsigned* __restrict__ packed, int e, int lane) {
    int eu  = __builtin_amdgcn_readfirstlane(e);
    int beg = row_ptr[eu];
    int end = row_ptr[eu + 1];
    int len = end - beg;
    if (len == 0) return 0.0f;
    float acc = 0.0f;
    if (len <= 64) {
        unsigned pv = (lane < len) ? packed[beg + lane] : 0u;
        int j = 0;
        for (; j + 8 <= len; j += 8) {
            float xv[8], rv[8];
            #pragma unroll
            for (int u = 0; u < 8; ++u) {
                unsigned p = __shfl(pv, j + u);
                xv[u] = xT[(size_t)(p & 0x3FFFFu) * 64 + lane];
                rv[u] = rT[(size_t)(p >> 18) * 64 + lane];
            }
            #pragma unroll
            for (int u = 0; u < 8; ++u) acc = fmaf(xv[u], rv[u], acc);
        }
        int rem = len - j;   // 0..7
        if (rem > 0) {
            float xv[8], rv[8];
            #pragma unroll
            for (int u = 0; u < 8; ++u) {
                int idx = j + ((u < rem) ? u : rem - 1);   // clamp: dup of last, cache-hit
                unsigned p = __shfl(pv, idx);
                xv[u] = xT[(size_t)(p & 0x3FFFFu) * 64 + lane];
                rv[u] = rT[(size_t)(p >> 18) * 64 + lane];
            }
            #pragma unroll
            for (int u = 0; u < 8; ++u)
                if (u < rem) acc = fmaf(xv[u], rv[u], acc);
        }
    } else {
        int i = beg;
        for (; i + 8 <= end; i += 8) {
            float xv[8], rv[8];
            #pragma unroll
            for (int u = 0; u < 8; ++u) {
                unsigned p = packed[i + u];
                xv[u] = xT[(size_t)(p & 0x3FFFFu) * 64 + lane];
                rv[u] = rT[(size_t)(p >> 18) * 64 + lane];
            }
            #pragma unroll
            for (int u = 0; u < 8; ++u) acc = fmaf(xv[u], rv[u], acc);
        }
        for (; i < end; ++i) {
            unsigned p = packed[i];
            acc = fmaf(xT[(size_t)(p & 0x3FFFFu) * 64 + lane],
                       rT[(size_t)(p >> 18) * 64 + lane], acc);
        }
    }
    return acc;
}

// hops 1-2: one wave per entity, output in (N_E, 64) layout
__global__ void hop_csr_kernel(const float* __restrict__ xT, const float* __restrict__ rT,
                               const int* __restrict__ row_ptr, const unsigned* __restrict__ packed,
                               float* __restrict__ yT, int nE) {
    int lane = threadIdx.x & 63;
    int e = (blockIdx.x * blockDim.x + threadIdx.x) >> 6;
    if (e >= nE) return;
    yT[(size_t)e * 64 + lane] = hop_accum(xT, rT, row_ptr, packed, e, lane);
}

// hop 3 fused with output transpose: block handles 64 entities, accumulates
// into an LDS tile, stores directly in (B, N_E) layout.
__global__ void hop_csr_out_kernel(const float* __restrict__ xT, const float* __restrict__ rT,
                                   const int* __restrict__ row_ptr, const unsigned* __restrict__ packed,
                                   float* __restrict__ out, int nE) {
    __shared__ float tile[64][65];
    int lane = threadIdx.x & 63;
    int wv   = threadIdx.x >> 6;    // 0..3
    int e0   = blockIdx.x * 64;
    for (int i = wv; i < 64; i += 4) {
        int e = e0 + i;
        tile[i][lane] = (e < nE) ? hop_accum(xT, rT, row_ptr, packed, e, lane) : 0.0f;
    }
    __syncthreads();
    #pragma unroll
    for (int k = 0; k < 16; ++k) {
        int b = wv + 4 * k;
        int e = e0 + lane;
        if (e < nE) out[(size_t)b * nE + e] = tile[lane][b];
    }
}

extern "C" void kernel_launch(void* const* d_in, const int* in_sizes, int n_in,
                              void* d_out, int out_size, void* d_ws, size_t ws_size,
                              hipStream_t stream) {
    const float* x  = (const float*)d_in[0];
    const float* q  = (const float*)d_in[1];
    const float* W1 = (const float*)d_in[2];
    const float* b1 = (const float*)d_in[3];
    const float* W2 = (const float*)d_in[4];
    const float* b2 = (const float*)d_in[5];
    const float* W3 = (const float*)d_in[6];
    const float* b3 = (const float*)d_in[7];
    const int* subj = (const int*)d_in[8];
    const int* rel  = (const int*)d_in[9];
    const int* obj  = (const int*)d_in[10];
    // n_hop (d_in[11]) is the constant 3 per the reference; hops hardcoded.

    const int B     = 64;
    const int N_E   = in_sizes[0] / B;   // 200000
    const int N_W2V = in_sizes[1] / B;   // 300
    const int N_R   = in_sizes[3];       // 200
    const int N_T   = in_sizes[8];       // 1000000

    const size_t xelems = (size_t)N_E * B;
    const size_t xbytes = xelems * sizeof(float);

    // workspace layout: [counts nE][row_ptr nE+1][cursor nE][packed nT][rT][bufA][bufB?]
    int*      counts  = (int*)d_ws;
    int*      row_ptr = counts + N_E;
    int*      cursor  = row_ptr + (N_E + 1);
    unsigned* packed  = (unsigned*)(cursor + N_E);
    float*    rT      = (float*)(packed + N_T);
    float*    bufA    = rT + (size_t)3 * N_R * B;
    size_t used = (size_t)((char*)bufA - (char*)d_ws) + xbytes;

    float* bufB;
    if (ws_size >= used + xbytes) {
        bufB = bufA + xelems;
    } else {
        bufB = (float*)d_out;   // mid-run scratch; final write is hop_csr_out
    }

    // scan partials: steal tail of ws if free, else tail of packed (safe:
    // packed written only after scanC consumed partials).
    int nScan = (N_E + 255) / 256;       // 782
    int* partials = (int*)((char*)d_ws + ws_size - 4096);
    if ((size_t)((char*)partials - (char*)d_ws) < used + ((bufB == (float*)d_out) ? 0 : xbytes))
        partials = (int*)packed + (N_T - 1024);

    // 1) r for all three layers
    {
        dim3 rgrid((3 * N_R + 63) / 64, B / 4);
        compute_r_kernel<<<rgrid, 256, 0, stream>>>(q, W1, b1, W2, b2, W3, b3, rT, N_R, N_W2V);
    }

    // 2) transpose x -> bufA
    int tgrid = (N_E + 63) / 64;
    transpose_in_kernel<<<tgrid, 256, 0, stream>>>(x, bufA, N_E);

    // 3) CSR build (XCD-sharded count -> scan -> XCD-sharded scatter)
    hipMemsetAsync(counts, 0, (size_t)N_E * sizeof(int), stream);
    count_kernel<<<1024, 256, 0, stream>>>(obj, counts, N_T, N_E);
    scanA_kernel<<<nScan, 256, 0, stream>>>(counts, partials, N_E);
    scanB_kernel<<<1, 1024, 0, stream>>>(partials, nScan);
    scanC_kernel<<<nScan, 256, 0, stream>>>(counts, partials, row_ptr, cursor, N_E);
    scatter_kernel<<<1024, 256, 0, stream>>>(subj, rel, obj, cursor, packed, N_T, N_E);

    // 4) three hops; hop3 fuses the output transpose
    int hgrid = ((N_E * 64) + 255) / 256;    // one wave per entity
    hop_csr_kernel<<<hgrid, 256, 0, stream>>>(bufA, rT,                       row_ptr, packed, bufB, N_E);
    hop_csr_kernel<<<hgrid, 256, 0, stream>>>(bufB, rT + (size_t)1 * N_R * B, row_ptr, packed, bufA, N_E);
    hop_csr_out_kernel<<<tgrid, 256, 0, stream>>>(bufA, rT + (size_t)2 * N_R * B, row_ptr, packed,
                                                  (float*)d_out, N_E);
}

// Round 8
// 445.231 us; speedup vs baseline: 6.3427x; 1.0223x over previous
//
#include <hip/hip_runtime.h>

#define WAVE 64
#define NXCD 8

// rT layout: [layer][N_R][64]  (batch innermost, matches lane)
__global__ void compute_r_kernel(const float* __restrict__ q,
                                 const float* __restrict__ W1, const float* __restrict__ b1,
                                 const float* __restrict__ W2, const float* __restrict__ b2,
                                 const float* __restrict__ W3, const float* __restrict__ b3,
                                 float* __restrict__ rT, int N_R, int N_W2V) {
    int lane = threadIdx.x & 63;
    int wv   = threadIdx.x >> 6;
    int b    = blockIdx.y * 4 + wv;
    int it   = blockIdx.x * 64 + lane;
    if (it >= 3 * N_R) return;
    int l = it / N_R;
    int j = it - l * N_R;
    const float* W  = (l == 0) ? W1 : (l == 1) ? W2 : W3;
    const float* bv = (l == 0) ? b1 : (l == 1) ? b2 : b3;
    const float* qrow = q + (size_t)b * N_W2V;
    float a0 = 0.f, a1 = 0.f, a2 = 0.f, a3 = 0.f;
    int k = 0;
    for (; k + 4 <= N_W2V; k += 4) {
        a0 = fmaf(qrow[k + 0], W[(size_t)(k + 0) * N_R + j], a0);
        a1 = fmaf(qrow[k + 1], W[(size_t)(k + 1) * N_R + j], a1);
        a2 = fmaf(qrow[k + 2], W[(size_t)(k + 2) * N_R + j], a2);
        a3 = fmaf(qrow[k + 3], W[(size_t)(k + 3) * N_R + j], a3);
    }
    for (; k < N_W2V; ++k)
        a0 = fmaf(qrow[k], W[(size_t)k * N_R + j], a0);
    rT[(size_t)it * WAVE + b] = bv[j] + ((a0 + a1) + (a2 + a3));
}

// x (B=64, N_E) -> xT (N_E, 64)
__global__ void transpose_in_kernel(const float* __restrict__ in, float* __restrict__ out, int N_E) {
    __shared__ float tile[64][65];
    int e0 = blockIdx.x * 64;
    int li = threadIdx.x & 63;
    int lo = threadIdx.x >> 6;
    #pragma unroll
    for (int k = 0; k < 16; ++k) {
        int b = lo + 4 * k;
        int e = e0 + li;
        tile[b][li] = (e < N_E) ? in[(size_t)b * N_E + e] : 0.0f;
    }
    __syncthreads();
    #pragma unroll
    for (int k = 0; k < 16; ++k) {
        int i = lo + 4 * k;
        int e = e0 + i;
        if (e < N_E) out[(size_t)e * 64 + li] = tile[li][i];
    }
}

// ---- CSR build ----
// R5 lesson: un-sharded random 4B scatter writes cost 17x HBM write
// amplification (64B lines dirtied in multiple non-coherent XCD L2s).
// Group g = blockIdx%8 owns entity range; only touches its own slice.

__global__ void count_kernel(const int* __restrict__ obj, int* __restrict__ counts,
                             int nT, int nE) {
    int grp = blockIdx.x & (NXCD - 1);
    int sh  = (nE + NXCD - 1) / NXCD;
    int lo  = grp * sh;
    int hi  = min(nE, lo + sh);
    int tid    = (blockIdx.x >> 3) * blockDim.x + threadIdx.x;
    int stride = (gridDim.x >> 3) * blockDim.x;
    for (int t = tid; t < nT; t += stride) {
        int o = obj[t];
        if (o >= lo && o < hi) atomicAdd(&counts[o], 1);
    }
}

__global__ void scanA_kernel(const int* __restrict__ counts, int* __restrict__ partials, int nE) {
    __shared__ int lds[256];
    int i = blockIdx.x * 256 + threadIdx.x;
    lds[threadIdx.x] = (i < nE) ? counts[i] : 0;
    __syncthreads();
    for (int off = 128; off > 0; off >>= 1) {
        if (threadIdx.x < off) lds[threadIdx.x] += lds[threadIdx.x + off];
        __syncthreads();
    }
    if (threadIdx.x == 0) partials[blockIdx.x] = lds[0];
}

// single block, nP <= 1024 (here nP = ceil(200000/256) = 782)
__global__ void scanB_kernel(int* __restrict__ partials, int nP) {
    __shared__ int lds[1024];
    int tid = threadIdx.x;
    lds[tid] = (tid < nP) ? partials[tid] : 0;
    __syncthreads();
    for (int off = 1; off < 1024; off <<= 1) {
        int v = (tid >= off) ? lds[tid - off] : 0;
        __syncthreads();
        lds[tid] += v;
        __syncthreads();
    }
    if (tid < nP) partials[tid] = (tid == 0) ? 0 : lds[tid - 1];
}

__global__ void scanC_kernel(const int* __restrict__ counts, const int* __restrict__ partials,
                             int* __restrict__ row_ptr, int* __restrict__ cursor, int nE) {
    __shared__ int lds[256];
    int i = blockIdx.x * 256 + threadIdx.x;
    int c = (i < nE) ? counts[i] : 0;
    lds[threadIdx.x] = c;
    __syncthreads();
    for (int off = 1; off < 256; off <<= 1) {
        int v = (threadIdx.x >= off) ? lds[threadIdx.x - off] : 0;
        __syncthreads();
        lds[threadIdx.x] += v;
        __syncthreads();
    }
    int excl = partials[blockIdx.x] + ((threadIdx.x == 0) ? 0 : lds[threadIdx.x - 1]);
    if (i < nE) { row_ptr[i] = excl; cursor[i] = excl; }
    if (i == nE - 1) row_ptr[nE] = excl + c;
}

// packed = subj | (rel<<18). Valid for N_E < 2^18, N_R < 2^14 (here 200000/200).
__global__ void scatter_kernel(const int* __restrict__ subj, const int* __restrict__ rel,
                               const int* __restrict__ obj, int* __restrict__ cursor,
                               unsigned* __restrict__ packed, int nT, int nE) {
    int grp = blockIdx.x & (NXCD - 1);
    int sh  = (nE + NXCD - 1) / NXCD;
    int lo  = grp * sh;
    int hi  = min(nE, lo + sh);
    int tid    = (blockIdx.x >> 3) * blockDim.x + threadIdx.x;
    int stride = (gridDim.x >> 3) * blockDim.x;
    for (int t = tid; t < nT; t += stride) {
        int o = obj[t];
        if (o >= lo && o < hi) {
            int slot = atomicAdd(&cursor[o], 1);
            packed[slot] = (unsigned)subj[t] | ((unsigned)rel[t] << 18);
        }
    }
}

// R8 hop shape: 4 entities per wave, 16 lanes x float4 per entity.
// Plain loads stay perfectly coalesced at 16B/lane (unlike R2's atomics),
// so one global_load_dwordx4 instruction now moves 4 triples' 256B rows
// (1KB/instr) -> ~4x fewer memory instructions per triple + 4 independent
// buckets in flight per wave. Indices staged 16/group in pv (len<=16 covers
// ~all of Poisson(5); slow-path loop for the rest). Zero atomics (R3).
__device__ inline float4 hop_accum4(const float4* __restrict__ xT4, const float4* __restrict__ rT4,
                                    const int* __restrict__ row_ptr,
                                    const unsigned* __restrict__ packed,
                                    int e, int g, int c, int nE) {
    float4 acc = make_float4(0.f, 0.f, 0.f, 0.f);
    bool ev = e < nE;
    int beg = ev ? row_ptr[e] : 0;
    int end = ev ? row_ptr[e + 1] : 0;
    int len = end - beg;
    unsigned pv = (c < len) ? packed[beg + c] : 0u;   // stage first 16 idx of this group's bucket
    int n16 = min(len, 16);
    int m = max(n16, __shfl_xor(n16, 16));            // wave-max over the 4 groups
    m = max(m, __shfl_xor(m, 32));
    for (int j0 = 0; j0 < m; j0 += 4) {
        float4 xv[4], rv[4];
        #pragma unroll
        for (int u = 0; u < 4; ++u) {
            int jj = max(min(j0 + u, len - 1), 0);    // clamp: dup loads hit hot lines
            unsigned p = __shfl(pv, (g << 4) + jj);   // per-lane src index: group-local broadcast
            xv[u] = xT4[(size_t)(p & 0x3FFFFu) * 16 + c];
            rv[u] = rT4[(size_t)(p >> 18) * 16 + c];
        }
        #pragma unroll
        for (int u = 0; u < 4; ++u) {
            if (j0 + u < len) {
                acc.x = fmaf(xv[u].x, rv[u].x, acc.x);
                acc.y = fmaf(xv[u].y, rv[u].y, acc.y);
                acc.z = fmaf(xv[u].z, rv[u].z, acc.z);
                acc.w = fmaf(xv[u].w, rv[u].w, acc.w);
            }
        }
    }
    // rare overflow (len > 16): per-group sequential, wave votes to exit
    int j = 16;
    while (__any(j < len)) {
        if (j < len) {
            unsigned p = packed[beg + j];
            float4 xv = xT4[(size_t)(p & 0x3FFFFu) * 16 + c];
            float4 rv = rT4[(size_t)(p >> 18) * 16 + c];
            acc.x = fmaf(xv.x, rv.x, acc.x);
            acc.y = fmaf(xv.y, rv.y, acc.y);
            acc.z = fmaf(xv.z, rv.z, acc.z);
            acc.w = fmaf(xv.w, rv.w, acc.w);
        }
        ++j;
    }
    return acc;
}

// hops 1-2: output in (N_E, 64) layout; wave stores 4 entities = 1KB contiguous
__global__ void hop_csr_kernel(const float4* __restrict__ xT4, const float4* __restrict__ rT4,
                               const int* __restrict__ row_ptr, const unsigned* __restrict__ packed,
                               float4* __restrict__ yT4, int nE) {
    int lane = threadIdx.x & 63;
    int g = lane >> 4, c = lane & 15;
    int w = (blockIdx.x * blockDim.x + threadIdx.x) >> 6;
    int e = w * 4 + g;
    float4 acc = hop_accum4(xT4, rT4, row_ptr, packed, e, g, c, nE);
    if (e < nE) yT4[(size_t)e * 16 + c] = acc;
}

// hop 3 fused with output transpose: block covers 64 entities via LDS tile,
// stores directly in (B, N_E) layout.
__global__ void hop_csr_out_kernel(const float4* __restrict__ xT4, const float4* __restrict__ rT4,
                                   const int* __restrict__ row_ptr, const unsigned* __restrict__ packed,
                                   float* __restrict__ out, int nE) {
    __shared__ float tile[64][65];
    int lane = threadIdx.x & 63;
    int wv   = threadIdx.x >> 6;    // 0..3
    int g = lane >> 4, c = lane & 15;
    int e0 = blockIdx.x * 64;
    for (int it = 0; it < 4; ++it) {
        int ei = it * 16 + wv * 4 + g;              // 0..63, unique per (it,wv,g)
        int e  = e0 + ei;
        float4 acc = hop_accum4(xT4, rT4, row_ptr, packed, e, g, c, nE);
        tile[ei][4 * c + 0] = acc.x;
        tile[ei][4 * c + 1] = acc.y;
        tile[ei][4 * c + 2] = acc.z;
        tile[ei][4 * c + 3] = acc.w;
    }
    __syncthreads();
    #pragma unroll
    for (int k = 0; k < 16; ++k) {
        int b = wv + 4 * k;
        int e = e0 + lane;
        if (e < nE) out[(size_t)b * nE + e] = tile[lane][b];
    }
}

extern "C" void kernel_launch(void* const* d_in, const int* in_sizes, int n_in,
                              void* d_out, int out_size, void* d_ws, size_t ws_size,
                              hipStream_t stream) {
    const float* x  = (const float*)d_in[0];
    const float* q  = (const float*)d_in[1];
    const float* W1 = (const float*)d_in[2];
    const float* b1 = (const float*)d_in[3];
    const float* W2 = (const float*)d_in[4];
    const float* b2 = (const float*)d_in[5];
    const float* W3 = (const float*)d_in[6];
    const float* b3 = (const float*)d_in[7];
    const int* subj = (const int*)d_in[8];
    const int* rel  = (const int*)d_in[9];
    const int* obj  = (const int*)d_in[10];
    // n_hop (d_in[11]) is the constant 3 per the reference; hops hardcoded.

    const int B     = 64;
    const int N_E   = in_sizes[0] / B;   // 200000
    const int N_W2V = in_sizes[1] / B;   // 300
    const int N_R   = in_sizes[3];       // 200
    const int N_T   = in_sizes[8];       // 1000000

    const size_t xelems = (size_t)N_E * B;
    const size_t xbytes = xelems * sizeof(float);

    // ws layout: [counts nE][row_ptr nE+4 (pad keeps rT 16B-aligned)][cursor nE]
    //            [packed nT][rT 3*N_R*64][bufA][bufB?]
    int*      counts  = (int*)d_ws;
    int*      row_ptr = counts + N_E;
    int*      cursor  = row_ptr + (N_E + 4);
    unsigned* packed  = (unsigned*)(cursor + N_E);
    float*    rT      = (float*)(packed + N_T);          // 16B-aligned by construction
    float*    bufA    = rT + (size_t)3 * N_R * B;
    size_t used = (size_t)((char*)bufA - (char*)d_ws) + xbytes;

    float* bufB;
    if (ws_size >= used + xbytes) {
        bufB = bufA + xelems;
    } else {
        bufB = (float*)d_out;   // mid-run scratch; final write is hop_csr_out
    }

    // scan partials: steal tail of ws if free, else tail of packed (safe:
    // packed written only after scanC consumed partials).
    int nScan = (N_E + 255) / 256;       // 782
    int* partials = (int*)((char*)d_ws + ws_size - 4096);
    if ((size_t)((char*)partials - (char*)d_ws) < used + ((bufB == (float*)d_out) ? 0 : xbytes))
        partials = (int*)packed + (N_T - 1024);

    // 1) r for all three layers
    {
        dim3 rgrid((3 * N_R + 63) / 64, B / 4);
        compute_r_kernel<<<rgrid, 256, 0, stream>>>(q, W1, b1, W2, b2, W3, b3, rT, N_R, N_W2V);
    }

    // 2) transpose x -> bufA
    int tgrid = (N_E + 63) / 64;
    transpose_in_kernel<<<tgrid, 256, 0, stream>>>(x, bufA, N_E);

    // 3) CSR build (XCD-sharded count -> scan -> XCD-sharded scatter)
    hipMemsetAsync(counts, 0, (size_t)N_E * sizeof(int), stream);
    count_kernel<<<1024, 256, 0, stream>>>(obj, counts, N_T, N_E);
    scanA_kernel<<<nScan, 256, 0, stream>>>(counts, partials, N_E);
    scanB_kernel<<<1, 1024, 0, stream>>>(partials, nScan);
    scanC_kernel<<<nScan, 256, 0, stream>>>(counts, partials, row_ptr, cursor, N_E);
    scatter_kernel<<<1024, 256, 0, stream>>>(subj, rel, obj, cursor, packed, N_T, N_E);

    // 4) three hops; hop3 fuses the output transpose
    int nwaves = (N_E + 3) / 4;                    // 4 entities per wave
    int hgrid  = (nwaves + 3) / 4;                 // 4 waves per 256-thread block
    hop_csr_kernel<<<hgrid, 256, 0, stream>>>((const float4*)bufA, (const float4*)rT,
                                              row_ptr, packed, (float4*)bufB, N_E);
    hop_csr_kernel<<<hgrid, 256, 0, stream>>>((const float4*)bufB, (const float4*)(rT + (size_t)1 * N_R * B),
                                              row_ptr, packed, (float4*)bufA, N_E);
    hop_csr_out_kernel<<<tgrid, 256, 0, stream>>>((const float4*)bufA, (const float4*)(rT + (size_t)2 * N_R * B),
                                                  row_ptr, packed, (float*)d_out, N_E);
}